// Round 10
// baseline (1009.978 us; speedup 1.0000x reference)
//
#include <hip/hip_runtime.h>
#include <hip/hip_bf16.h>

#define K 5
#define F 64
#define EMBD 200
#define HID 256
#define NH 3
#define NL 3
#define CB 8            // crystals per block for POOL kernels
#define NB (CB * K)     // 40 nodes per pool block

// layer kernel: 4 waves x 3 crystals = 12 crystals / block
#define CW 3            // crystals per wave
#define NWN (CW * K)    // 15 nodes per wave
#define EWE (CW * K * K) // 75 edges per wave
#define ET 5            // edge tiles of 16

typedef _Float16 half8 __attribute__((ext_vector_type(8)));
typedef float f32x4 __attribute__((ext_vector_type(4)));

__device__ __forceinline__ float lrelu(float v) { return v >= 0.f ? v : 0.01f * v; }

__device__ __forceinline__ half8 lrelu8(half8 t) {
    half8 z = 0;
    half8 p = __builtin_elementwise_max(t, z);
    half8 n = __builtin_elementwise_min(t, z);
    return p + n * (_Float16)0.01f;
}

// ---- swizzled-weight element counts (fp16) ----
#define W1SW_ELEMS 589824    // 9 lh * 2 net * 2 half * 4 chunk * 4 nt * 2 ks * 64 * 8
#define W2SW_ELEMS 147456    // 9 lh * 8 ks2 * 4 nt * 64 * 8
#define CW1_ELEMS   98304    // 3 h * 2 net * 4 chunk * 4 nt * 2 ks * 64 * 8
#define CW2_ELEMS   49152    // 3 h * 8 ks2 * 4 nt * 64 * 8
#define WALL_ELEMS (W1SW_ELEMS + W2SW_ELEMS + CW1_ELEMS + CW2_ELEMS)  // 884736

// per-layer (fallback) sizes
#define W1L_ELEMS 196608
#define W2L_ELEMS 49152

// ---------------------------------------------------------------------------
// Fast path: swizzle ALL weights (layers + pool) fp32 -> fp16 B-frag order.
// ---------------------------------------------------------------------------
__global__ __launch_bounds__(256)
void prep_all(const float* __restrict__ gW1, const float* __restrict__ mW1,
              const float* __restrict__ mW2,
              const float* __restrict__ cgW1, const float* __restrict__ cmW1,
              const float* __restrict__ cmW2,
              _Float16* __restrict__ Wall)
{
    int tid = blockIdx.x * 256 + threadIdx.x;
    if (tid >= WALL_ELEMS) return;
    float v;
    if (tid < W1SW_ELEMS) {
        int j = tid & 7, lane = (tid >> 3) & 63;
        int r1 = tid >> 9;                       // [lh][net][half][chunk][nt][ks]
        int ks = r1 & 1, nt = (r1 >> 1) & 3, chunk = (r1 >> 3) & 3;
        int half = (r1 >> 5) & 1, net = (r1 >> 6) & 1, lh = r1 >> 7;   // 0..8
        int q = lane >> 4, n16 = lane & 15;
        const float* src = net ? mW1 : gW1;
        v = src[((size_t)lh * 128 + half * 64 + ks * 32 + q * 8 + j) * 256
                + chunk * 64 + nt * 16 + n16];
    } else if (tid < W1SW_ELEMS + W2SW_ELEMS) {
        int t2 = tid - W1SW_ELEMS;
        int j = t2 & 7, lane = (t2 >> 3) & 63;
        int r1 = t2 >> 9;                        // [lh][ks2][nt]
        int nt = r1 & 3, ks2 = (r1 >> 2) & 7, lh = r1 >> 5;            // 0..8
        int q = lane >> 4, n16 = lane & 15;
        v = mW2[((size_t)lh * 256 + ks2 * 32 + q * 8 + j) * 64 + nt * 16 + n16];
    } else if (tid < W1SW_ELEMS + W2SW_ELEMS + CW1_ELEMS) {
        int t2 = tid - (W1SW_ELEMS + W2SW_ELEMS);
        int j = t2 & 7, lane = (t2 >> 3) & 63;
        int r1 = t2 >> 9;                        // [h][net][chunk][nt][ks]
        int ks = r1 & 1, nt = (r1 >> 1) & 3, chunk = (r1 >> 3) & 3;
        int net = (r1 >> 5) & 1, h = r1 >> 6;                          // 0..2
        int q = lane >> 4, n16 = lane & 15;
        const float* src = net ? cmW1 : cgW1;
        v = src[((size_t)h * 64 + ks * 32 + q * 8 + j) * 256
                + chunk * 64 + nt * 16 + n16];
    } else {
        int t2 = tid - (W1SW_ELEMS + W2SW_ELEMS + CW1_ELEMS);
        int j = t2 & 7, lane = (t2 >> 3) & 63;
        int r1 = t2 >> 9;                        // [h][ks2][nt]
        int nt = r1 & 3, ks2 = (r1 >> 2) & 7, h = r1 >> 5;             // 0..2
        int q = lane >> 4, n16 = lane & 15;
        v = cmW2[((size_t)h * 256 + ks2 * 32 + q * 8 + j) * 64 + nt * 16 + n16];
    }
    Wall[tid] = (_Float16)v;
}

// ---------------------------------------------------------------------------
// Fallback: per-layer prep into d_out scratch (round-4 proven).
// ---------------------------------------------------------------------------
__global__ __launch_bounds__(256)
void prep_layer(const float* __restrict__ gW1, const float* __restrict__ mW1,
                const float* __restrict__ mW2,
                _Float16* __restrict__ W1sw, _Float16* __restrict__ W2sw, int l)
{
    int tid = blockIdx.x * 256 + threadIdx.x;
    if (tid < W1L_ELEMS) {
        int j = tid & 7, lane = (tid >> 3) & 63;
        int r1 = tid >> 9;
        int ks = r1 & 1, nt = (r1 >> 1) & 3, chunk = (r1 >> 3) & 3;
        int half = (r1 >> 5) & 1, net = (r1 >> 6) & 1, hh = r1 >> 7;
        int q = lane >> 4, n16 = lane & 15;
        const float* src = net ? mW1 : gW1;
        float v = src[((size_t)(l * NH + hh) * 128 + half * 64 + ks * 32 + q * 8 + j) * 256
                      + chunk * 64 + nt * 16 + n16];
        W1sw[tid] = (_Float16)v;
    } else {
        int t2 = tid - W1L_ELEMS;
        if (t2 < W2L_ELEMS) {
            int j = t2 & 7, lane = (t2 >> 3) & 63;
            int r1 = t2 >> 9;
            int nt = r1 & 3, ks2 = (r1 >> 2) & 7, hh = r1 >> 5;
            int q = lane >> 4, n16 = lane & 15;
            float v = mW2[((size_t)(l * NH + hh) * 256 + ks2 * 32 + q * 8 + j) * 64
                          + nt * 16 + n16];
            W2sw[t2] = (_Float16)v;
        }
    }
}

// ---------------------------------------------------------------------------
// Embedding
// ---------------------------------------------------------------------------
__global__ __launch_bounds__(64)
void embed_kernel(const float* __restrict__ fea, const float* __restrict__ W,
                  const float* __restrict__ b, const float* __restrict__ wts,
                  float* __restrict__ x)
{
    int n = blockIdx.x;
    int o = threadIdx.x;
    __shared__ float fs[EMBD];
    for (int e = o; e < EMBD; e += 64) fs[e] = fea[n * EMBD + e];
    __syncthreads();
    if (o < F - 1) {
        float acc = b[o];
#pragma unroll 8
        for (int e = 0; e < EMBD; ++e) acc += fs[e] * W[e * (F - 1) + o];
        x[n * F + o] = acc;
    } else {
        x[n * F + F - 1] = wts[n];
    }
}

// ---------------------------------------------------------------------------
// One graph layer. 4 waves / block, each wave owns 3 crystals end-to-end.
// NEW: stage-1 weights staged COOPERATIVELY into block-shared LDS each chunk
// (each wave loads net-half w's 8 frags, 16 B/lane coalesced, ds_write).
// Stage-1 MFMA B comes from ds_read_b128 (~12 cyc) instead of serialized
// global loads (~300+ cyc). Two __syncthreads per chunk guard only the 32 KB
// weight buffer; all per-crystal state stays wave-private.
// ---------------------------------------------------------------------------
#define WAVE_SLICE 10944   // bytes per wave-private slice

__global__ __launch_bounds__(256)
void layer_wave(float* __restrict__ x,
                const _Float16* __restrict__ W1sw,
                const _Float16* __restrict__ W2sw,
                const float* __restrict__ gb1, const float* __restrict__ gb2v,
                const float* __restrict__ mb1, const float* __restrict__ mb2,
                const float* __restrict__ gW2, const float* __restrict__ gpw,
                const float* __restrict__ wts, int l, int lhw0, int Ntot)
{
    __shared__ __align__(16) _Float16 W1b[32 * 64 * 8];   // 32 KB staged stage-1 B
    __shared__ __align__(16) char smem[4 * WAVE_SLICE];   // 42.75 KB wave slices

    const int t = threadIdx.x, w = t >> 6, lane = t & 63;
    const int q = lane >> 4, m16 = lane & 15;

    char* wb = smem + w * WAVE_SLICE;
    _Float16 (*PQ)[16][72] = (_Float16 (*)[16][72])wb;   // [4][16][72] = 9216 B
    _Float16 (*msgL)[66]   = (_Float16 (*)[66])wb;       // [80][66] = 10560 B (aliases PQ)
    float* gateS  = (float*)(wb + 9216);                 // [80] — inside msgL region, dead-phase alias
    float* anormS = (float*)(wb + 10560);                // [80]
    float* wpowS  = (float*)(wb + 10880);                // [16]

    const int nw0 = (blockIdx.x * 12 + w * CW) * K;      // first node of this wave
    const int vn  = (Ntot - nw0 < NWN) ? (Ntot - nw0) : NWN;

    // ---- A-fragments of x (head/half-invariant), fp16, loaded once ----
    half8 A[2];
    {
        int arow = nw0 + m16;
        if (arow > Ntot - 1) arow = Ntot - 1;
        if (arow < 0) arow = 0;
        const float* xr = x + (size_t)arow * F;
#pragma unroll
        for (int ks = 0; ks < 2; ++ks) {
            float4 f0 = *(const float4*)(xr + ks * 32 + q * 8);
            float4 f1 = *(const float4*)(xr + ks * 32 + q * 8 + 4);
            half8 a;
            a[0] = (_Float16)f0.x; a[1] = (_Float16)f0.y;
            a[2] = (_Float16)f0.z; a[3] = (_Float16)f0.w;
            a[4] = (_Float16)f1.x; a[5] = (_Float16)f1.y;
            a[6] = (_Float16)f1.z; a[7] = (_Float16)f1.w;
            A[ks] = a;
        }
    }

    // ---- per-lane edge -> local node rows ----
    int iR[ET], jR[ET];
#pragma unroll
    for (int et = 0; et < ET; ++et) {
        int e = et * 16 + m16;
        if (e < EWE) {
            int cl = e / 25, rm = e % 25;
            iR[et] = cl * K + rm / K;
            jR[et] = cl * K + rm % K;
        } else { iR[et] = 15; jR[et] = 15; }
    }

    float oacc[NWN];
#pragma unroll
    for (int n = 0; n < NWN; ++n) oacc[n] = 0.f;

    for (int h = 0; h < NH; ++h) {
        const int lh = l * NH + h, lhw = lhw0 + h;

        if (lane < NWN) {
            int wi = nw0 + lane;
            if (wi > Ntot - 1) wi = Ntot - 1;
            if (wi < 0) wi = 0;
            wpowS[lane] = powf(wts[wi], gpw[lh]);
        }
        if (lane >= NWN && lane < NWN + 5) anormS[EWE + (lane - NWN)] = 0.f;

        f32x4 acc2[ET][4];
#pragma unroll
        for (int et = 0; et < ET; ++et)
#pragma unroll
            for (int nt = 0; nt < 4; ++nt) acc2[et][nt] = (f32x4){0.f, 0.f, 0.f, 0.f};
        float gacc[ET] = {0.f, 0.f, 0.f, 0.f, 0.f};

        for (int c = 0; c < 4; ++c) {
            // ---- barrier: previous chunk's W1b reads complete in all waves ----
            __syncthreads();

            // ---- cooperative staging: wave w stages net-half w's 8 frags ----
            {
                const _Float16* Wsrc = W1sw + ((size_t)lhw * 4 + w) * 16384 + c * 4096;
                half8 tmp[8];
#pragma unroll
                for (int r = 0; r < 8; ++r)
                    tmp[r] = *(const half8*)(Wsrc + (r * 64 + lane) * 8);
#pragma unroll
                for (int r = 0; r < 8; ++r)
                    *(half8*)&W1b[((w * 8 + r) * 64 + lane) * 8] = tmp[r];
            }

            // ---- GEMM2 B-frags (global, L1-hot across waves; drain at barrier) ----
            half8 B2[8];
            {
                const _Float16* W2b = W2sw + ((size_t)lhw * 8 + c * 2) * 2048;
#pragma unroll
                for (int f = 0; f < 8; ++f)
                    B2[f] = *(const half8*)(W2b + ((size_t)f * 64 + lane) * 8);
            }

            // ---- barrier: W1b fully staged ----
            __syncthreads();

            // ---- stage-1: all 4 net-halves, B from LDS ----
#pragma unroll
            for (int hf = 0; hf < 4; ++hf) {
                f32x4 accS[4];
#pragma unroll
                for (int nt = 0; nt < 4; ++nt) accS[nt] = (f32x4){0.f, 0.f, 0.f, 0.f};
#pragma unroll
                for (int nt = 0; nt < 4; ++nt)
#pragma unroll
                    for (int ks = 0; ks < 2; ++ks) {
                        half8 B = *(const half8*)&W1b[((hf * 8 + nt * 2 + ks) * 64 + lane) * 8];
                        accS[nt] = __builtin_amdgcn_mfma_f32_16x16x32_f16(
                            A[ks], B, accS[nt], 0, 0, 0);
                    }
#pragma unroll
                for (int nt = 0; nt < 4; ++nt)
#pragma unroll
                    for (int rg = 0; rg < 4; ++rg)
                        PQ[hf][q * 4 + rg][nt * 16 + m16] = (_Float16)accS[nt][rg];
            }

            // ---- per-chunk bias slices (global, L1-hot) ----
            half8 bg8[2], bm8[2];
            float wg[2][8];
#pragma unroll
            for (int ks = 0; ks < 2; ++ks) {
                const int ub = c * 64 + ks * 32 + q * 8;
                float4 g0 = *(const float4*)(gb1 + (size_t)lh * HID + ub);
                float4 g1 = *(const float4*)(gb1 + (size_t)lh * HID + ub + 4);
                float4 m0 = *(const float4*)(mb1 + (size_t)lh * HID + ub);
                float4 m1 = *(const float4*)(mb1 + (size_t)lh * HID + ub + 4);
                float4 w0 = *(const float4*)(gW2 + (size_t)lh * HID + ub);
                float4 w1 = *(const float4*)(gW2 + (size_t)lh * HID + ub + 4);
                half8 bg, bm;
                bg[0]=(_Float16)g0.x; bg[1]=(_Float16)g0.y; bg[2]=(_Float16)g0.z; bg[3]=(_Float16)g0.w;
                bg[4]=(_Float16)g1.x; bg[5]=(_Float16)g1.y; bg[6]=(_Float16)g1.z; bg[7]=(_Float16)g1.w;
                bm[0]=(_Float16)m0.x; bm[1]=(_Float16)m0.y; bm[2]=(_Float16)m0.z; bm[3]=(_Float16)m0.w;
                bm[4]=(_Float16)m1.x; bm[5]=(_Float16)m1.y; bm[6]=(_Float16)m1.z; bm[7]=(_Float16)m1.w;
                bg8[ks] = bg; bm8[ks] = bm;
                wg[ks][0]=w0.x; wg[ks][1]=w0.y; wg[ks][2]=w0.z; wg[ks][3]=w0.w;
                wg[ks][4]=w1.x; wg[ks][5]=w1.y; wg[ks][6]=w1.z; wg[ks][7]=w1.w;
            }

            // ---- consume: gate partial + hm A-frags + GEMM2 (B2 reused) ----
#pragma unroll
            for (int et = 0; et < ET; ++et) {
                half8 af[2];
#pragma unroll
                for (int ks = 0; ks < 2; ++ks) {
                    const int ub = ks * 32 + q * 8;
                    half8 pg = *(const half8*)&PQ[0][iR[et]][ub];
                    half8 qg = *(const half8*)&PQ[1][jR[et]][ub];
                    half8 pm = *(const half8*)&PQ[2][iR[et]][ub];
                    half8 qm = *(const half8*)&PQ[3][jR[et]][ub];
                    half8 tg = lrelu8(pg + qg + bg8[ks]);
#pragma unroll
                    for (int jj = 0; jj < 8; ++jj)
                        gacc[et] += (float)tg[jj] * wg[ks][jj];
                    af[ks] = lrelu8(pm + qm + bm8[ks]);
                }
#pragma unroll
                for (int nt = 0; nt < 4; ++nt)
#pragma unroll
                    for (int ks = 0; ks < 2; ++ks)
                        acc2[et][nt] = __builtin_amdgcn_mfma_f32_16x16x32_f16(
                            af[ks], B2[ks * 4 + nt], acc2[et][nt], 0, 0, 0);
            }
        }

        // ---- gate reduce across quads (wave-private from here on) ----
        const float gb2s = gb2v[lh];
#pragma unroll
        for (int et = 0; et < ET; ++et) {
            float g = gacc[et];
            g += __shfl_xor(g, 16);
            g += __shfl_xor(g, 32);
            if (q == 0) gateS[et * 16 + m16] = g + gb2s;
        }

        // ---- segment softmax: lane n (0..14) handles local node n ----
        if (lane < NWN) {
            const int cl5 = (lane / K) * K;
            float gg[K], mx = -1e30f;
#pragma unroll
            for (int jj = 0; jj < K; ++jj) {
                gg[jj] = gateS[lane * K + jj];
                mx = fmaxf(mx, gg[jj]);
            }
            float s = 0.f, wv[K];
#pragma unroll
            for (int jj = 0; jj < K; ++jj) {
                wv[jj] = wpowS[cl5 + jj] * expf(gg[jj] - mx);
                s += wv[jj];
            }
            float inv = 1.f / (s + 1e-10f) * (1.f / 3.f);
#pragma unroll
            for (int jj = 0; jj < K; ++jj) anormS[lane * K + jj] = wv[jj] * inv;
        }

        // ---- weighted msg -> msgL (clobbers gateS alias: gateS dead) ----
        float b2v[4];
#pragma unroll
        for (int nt = 0; nt < 4; ++nt) b2v[nt] = mb2[(size_t)lh * F + nt * 16 + m16];
#pragma unroll
        for (int et = 0; et < ET; ++et) {
            f32x4 an = *(const f32x4*)&anormS[et * 16 + q * 4];
#pragma unroll
            for (int nt = 0; nt < 4; ++nt)
#pragma unroll
                for (int rg = 0; rg < 4; ++rg) {
                    float v = (acc2[et][nt][rg] + b2v[nt]) * an[rg];
                    msgL[et * 16 + q * 4 + rg][nt * 16 + m16] = (_Float16)v;
                }
        }

        // ---- aggregate: lane = output col, 15 nodes x 5 edges ----
#pragma unroll
        for (int n = 0; n < NWN; ++n) {
            float s = 0.f;
#pragma unroll
            for (int jj = 0; jj < K; ++jj) s += (float)msgL[n * K + jj][lane];
            oacc[n] += s;
        }
    }

    // ---- residual + write back ----
#pragma unroll
    for (int n = 0; n < NWN; ++n) {
        if (n < vn) {
            size_t idx = (size_t)(nw0 + n) * F + lane;
            x[idx] = oacc[n] + x[idx];
        }
    }
}

// ---------------------------------------------------------------------------
// MFMA pool (round-5 proven)
// ---------------------------------------------------------------------------
__global__ __launch_bounds__(256)
void pool_mfma(const float* __restrict__ x,
               const _Float16* __restrict__ cW1sw,
               const _Float16* __restrict__ cW2sw,
               const float* __restrict__ cgb1, const float* __restrict__ cgb2v,
               const float* __restrict__ cmb1, const float* __restrict__ cmb2,
               const float* __restrict__ cgW2, const float* __restrict__ cpw,
               const float* __restrict__ wts, float* __restrict__ out)
{
    __shared__ __align__(16) _Float16 xh[48][72];
    __shared__ __align__(16) char PQraw[2 * 48 * 72 * 2];
    __shared__ float outacc[CB * F];
    __shared__ float b1gS[HID], b1mS[HID], w2gS[HID], b2mS[F];
    __shared__ float gateS[48], anormS[48], wpowS[48];

    _Float16 (*P)[48][72] = (_Float16 (*)[48][72])PQraw;
    _Float16 (*msgW)[72]  = (_Float16 (*)[72])PQraw;

    const int t = threadIdx.x, w = t >> 6, lane = t & 63;
    const int quad = lane >> 4, m16 = lane & 15;
    const int node0 = blockIdx.x * NB;

    for (int d = t; d < 48 * 64; d += 256) {
        int r = d >> 6, cc = d & 63;
        float v = (r < NB) ? x[(size_t)(node0 + r) * F + cc] : 0.f;
        xh[r][cc] = (_Float16)v;
    }
    for (int d = t; d < CB * F; d += 256) outacc[d] = 0.f;
    __syncthreads();

    half8 A[3][2];
#pragma unroll
    for (int Mt = 0; Mt < 3; ++Mt)
#pragma unroll
        for (int ks = 0; ks < 2; ++ks)
            A[Mt][ks] = *(const half8*)&xh[Mt * 16 + m16][ks * 32 + quad * 8];

    const int net = w >> 1, ntp = w & 1;

    for (int h = 0; h < NH; ++h) {
        if (t < HID) {
            b1gS[t] = cgb1[(size_t)h * HID + t];
            b1mS[t] = cmb1[(size_t)h * HID + t];
            w2gS[t] = cgW2[(size_t)h * HID + t];
        }
        if (t < F)  b2mS[t] = cmb2[(size_t)h * F + t];
        if (t < NB) wpowS[t] = powf(wts[node0 + t], cpw[h]);
        const float gb2s = cgb2v[h];

        f32x4 acc2[4];
#pragma unroll
        for (int nt = 0; nt < 4; ++nt) acc2[nt] = (f32x4){0.f, 0.f, 0.f, 0.f};
        float gacc = 0.f;

        for (int chunk = 0; chunk < 4; ++chunk) {
            {
                f32x4 accS[3][2];
#pragma unroll
                for (int Mt = 0; Mt < 3; ++Mt)
#pragma unroll
                    for (int n2 = 0; n2 < 2; ++n2) accS[Mt][n2] = (f32x4){0.f, 0.f, 0.f, 0.f};
                const _Float16* Wb = cW1sw + ((size_t)(h * 2 + net) * 4 + chunk) * 4096;
#pragma unroll
                for (int n2 = 0; n2 < 2; ++n2) {
                    int nt = ntp * 2 + n2;
#pragma unroll
                    for (int ks = 0; ks < 2; ++ks) {
                        half8 B = *(const half8*)(Wb + ((nt * 2 + ks) * 64 + lane) * 8);
#pragma unroll
                        for (int Mt = 0; Mt < 3; ++Mt)
                            accS[Mt][n2] = __builtin_amdgcn_mfma_f32_16x16x32_f16(
                                A[Mt][ks], B, accS[Mt][n2], 0, 0, 0);
                    }
                }
#pragma unroll
                for (int Mt = 0; Mt < 3; ++Mt)
#pragma unroll
                    for (int n2 = 0; n2 < 2; ++n2)
#pragma unroll
                        for (int rg = 0; rg < 4; ++rg)
                            P[net][Mt * 16 + quad * 4 + rg][(ntp * 2 + n2) * 16 + m16] =
                                (_Float16)accS[Mt][n2][rg];
            }
            __syncthreads();

            if (w < 3) {
                half8 af[2];
#pragma unroll
                for (int ks = 0; ks < 2; ++ks) {
                    const int ub = ks * 32 + quad * 8;
                    half8 pg = *(const half8*)&P[0][w * 16 + m16][ub];
                    half8 pm = *(const half8*)&P[1][w * 16 + m16][ub];
#pragma unroll
                    for (int j = 0; j < 8; ++j) {
                        int u = chunk * 64 + ub + j;
                        float gh = lrelu((float)pg[j] + b1gS[u]);
                        gacc += gh * w2gS[u];
                        float hv = lrelu((float)pm[j] + b1mS[u]);
                        af[ks][j] = (_Float16)hv;
                    }
                }
                const _Float16* W2b = cW2sw + (size_t)h * 16384 + chunk * 4096;
#pragma unroll
                for (int nt = 0; nt < 4; ++nt)
#pragma unroll
                    for (int ks = 0; ks < 2; ++ks) {
                        half8 B = *(const half8*)(W2b + ((size_t)(ks * 4 + nt) * 64 + lane) * 8);
                        acc2[nt] = __builtin_amdgcn_mfma_f32_16x16x32_f16(
                            af[ks], B, acc2[nt], 0, 0, 0);
                    }
            }
            __syncthreads();
        }

        if (w < 3) {
            float g = gacc;
            g += __shfl_xor(g, 16);
            g += __shfl_xor(g, 32);
            if (quad == 0) gateS[w * 16 + m16] = g + gb2s;
        }
        __syncthreads();

        if (t < CB) {
            float mx = -1e30f;
#pragma unroll
            for (int j = 0; j < K; ++j) mx = fmaxf(mx, gateS[t * K + j]);
            float s = 0.f, wv[K];
#pragma unroll
            for (int j = 0; j < K; ++j) {
                wv[j] = wpowS[t * K + j] * expf(gateS[t * K + j] - mx);
                s += wv[j];
            }
            float inv = 1.f / (s + 1e-10f) * (1.f / 3.f);
#pragma unroll
            for (int j = 0; j < K; ++j) anormS[t * K + j] = wv[j] * inv;
        }
        __syncthreads();

        if (w < 3) {
#pragma unroll
            for (int nt = 0; nt < 4; ++nt)
#pragma unroll
                for (int rg = 0; rg < 4; ++rg) {
                    int row = w * 16 + quad * 4 + rg;
                    float a = (row < NB) ? anormS[row] : 0.f;
                    float v = (acc2[nt][rg] + b2mS[nt * 16 + m16]) * a;
                    msgW[row][nt * 16 + m16] = (_Float16)v;
                }
        }
        __syncthreads();

        for (int d = t; d < CB * F; d += 256) {
            int cr = d >> 6, o = d & 63;
            float s = 0.f;
#pragma unroll
            for (int j = 0; j < K; ++j) s += (float)msgW[cr * K + j][o];
            outacc[d] += s;
        }
        __syncthreads();
    }

    for (int d = t; d < CB * F; d += 256)
        out[(size_t)blockIdx.x * (CB * F) + d] = outacc[d];
}

// ---------------------------------------------------------------------------
// Fallback fp32 pool (round-4 proven)
// ---------------------------------------------------------------------------
__global__ __launch_bounds__(256)
void pool_kernel(const float* __restrict__ x,
                 const float* __restrict__ cgW1, const float* __restrict__ cgb1,
                 const float* __restrict__ cgW2, const float* __restrict__ cgb2,
                 const float* __restrict__ cmW1, const float* __restrict__ cmb1,
                 const float* __restrict__ cmW2, const float* __restrict__ cmb2,
                 const float* __restrict__ cpw, const float* __restrict__ wts,
                 float* __restrict__ out)
{
    __shared__ float xs[K * F];
    __shared__ float hmS[K][HID];
    __shared__ float msgS[K][F];
    __shared__ float outacc[F];
    __shared__ float b1g[HID], b1m[HID], w2g[HID];
    __shared__ float b2mS[F];
    __shared__ float gpart[K][2];
    __shared__ float gate_s[K];
    __shared__ float anorm[K];
    __shared__ float wn[K], wpow[K];

    const int c = blockIdx.x;
    const int t = threadIdx.x;
    const int wave = t >> 6, lane = t & 63;

    for (int d = t; d < K * F; d += 256) xs[d] = x[c * K * F + d];
    if (t < F) outacc[t] = 0.f;
    if (t < K) wn[t] = wts[c * K + t];
    __syncthreads();

    for (int h = 0; h < NH; ++h) {
        if (t < HID) {
            b1g[t] = cgb1[(size_t)h * HID + t];
            b1m[t] = cmb1[(size_t)h * HID + t];
            w2g[t] = cgW2[(size_t)h * HID + t];
        }
        if (t < F) b2mS[t] = cmb2[(size_t)h * F + t];
        if (t < K) wpow[t] = powf(wn[t], cpw[h]);
        __syncthreads();

        {
            const int grp = t >> 7;
            const int up  = t & 127;
            const float* Wb = (grp == 0 ? cgW1 : cmW1) + (size_t)h * F * HID;
            const float2* W2p = (const float2*)Wb;
            float acc[K][2];
#pragma unroll
            for (int i = 0; i < K; ++i) { acc[i][0] = 0.f; acc[i][1] = 0.f; }
            for (int k = 0; k < F; ++k) {
                float2 wv = W2p[k * (HID / 2) + up];
#pragma unroll
                for (int i = 0; i < K; ++i) {
                    float xv = xs[i * F + k];
                    acc[i][0] += xv * wv.x;
                    acc[i][1] += xv * wv.y;
                }
            }
            if (grp == 0) {
#pragma unroll
                for (int i = 0; i < K; ++i) {
                    float h0 = lrelu(acc[i][0] + b1g[2 * up]);
                    float h1 = lrelu(acc[i][1] + b1g[2 * up + 1]);
                    float part = h0 * w2g[2 * up] + h1 * w2g[2 * up + 1];
#pragma unroll
                    for (int s = 32; s; s >>= 1) part += __shfl_xor(part, s);
                    if (lane == 0) gpart[i][wave & 1] = part;
                }
            } else {
#pragma unroll
                for (int i = 0; i < K; ++i) {
                    hmS[i][2 * up]     = lrelu(acc[i][0] + b1m[2 * up]);
                    hmS[i][2 * up + 1] = lrelu(acc[i][1] + b1m[2 * up + 1]);
                }
            }
        }
        __syncthreads();
        if (t < K) gate_s[t] = cgb2[h] + gpart[t][0] + gpart[t][1];

        {
            const float2* W232 = (const float2*)(cmW2 + (size_t)h * HID * F);
            if (t < K * (F / 2)) {
                int i  = t >> 5;
                int op = t & 31;
                float a0 = b2mS[2 * op], a1 = b2mS[2 * op + 1];
#pragma unroll 8
                for (int u = 0; u < HID; ++u) {
                    float2 wv = W232[u * (F / 2) + op];
                    float hv = hmS[i][u];
                    a0 += hv * wv.x;
                    a1 += hv * wv.y;
                }
                msgS[i][2 * op]     = a0;
                msgS[i][2 * op + 1] = a1;
            }
        }
        __syncthreads();

        if (t == 0) {
            float mx = -1e30f;
#pragma unroll
            for (int i = 0; i < K; ++i) mx = fmaxf(mx, gate_s[i]);
            float wv[K], s = 0.f;
#pragma unroll
            for (int i = 0; i < K; ++i) {
                wv[i] = wpow[i] * expf(gate_s[i] - mx);
                s += wv[i];
            }
            float inv = 1.f / (s + 1e-10f);
#pragma unroll
            for (int i = 0; i < K; ++i) anorm[i] = wv[i] * inv;
        }
        __syncthreads();

        if (t < F) {
            float s = 0.f;
#pragma unroll
            for (int i = 0; i < K; ++i) s += anorm[i] * msgS[i][t];
            outacc[t] += s * (1.f / 3.f);
        }
        __syncthreads();
    }

    if (t < F) out[(size_t)c * F + t] = outacc[t];
}

// ---------------------------------------------------------------------------
extern "C" void kernel_launch(void* const* d_in, const int* in_sizes, int n_in,
                              void* d_out, int out_size, void* d_ws, size_t ws_size,
                              hipStream_t stream)
{
    const float* wts  = (const float*)d_in[0];
    const float* fea  = (const float*)d_in[1];
    const float* embW = (const float*)d_in[6];
    const float* embB = (const float*)d_in[7];
    const float* gW1  = (const float*)d_in[8];
    const float* gb1  = (const float*)d_in[9];
    const float* gW2  = (const float*)d_in[10];
    const float* gb2  = (const float*)d_in[11];
    const float* mW1  = (const float*)d_in[12];
    const float* mb1  = (const float*)d_in[13];
    const float* mW2  = (const float*)d_in[14];
    const float* mb2  = (const float*)d_in[15];
    const float* gpw  = (const float*)d_in[16];
    const float* cgW1 = (const float*)d_in[17];
    const float* cgb1 = (const float*)d_in[18];
    const float* cgW2 = (const float*)d_in[19];
    const float* cgb2 = (const float*)d_in[20];
    const float* cmW1 = (const float*)d_in[21];
    const float* cmb1 = (const float*)d_in[22];
    const float* cmW2 = (const float*)d_in[23];
    const float* cmb2 = (const float*)d_in[24];
    const float* cpw  = (const float*)d_in[25];

    const int N = in_sizes[0];   // 50000
    const int C = N / K;         // 10000
    const int layer_blocks = (C + 11) / 12;   // 834 (tail block guarded)

    float* x = (float*)d_ws;                       // [N,F] fp32, 12.8 MB
    const size_t xbytes = (size_t)N * F * 4;
    const size_t need = xbytes + (size_t)WALL_ELEMS * 2;

    embed_kernel<<<N, 64, 0, stream>>>(fea, embW, embB, wts, x);

    if (ws_size >= need) {
        // ---- fast path ----
        _Float16* Wall  = (_Float16*)((char*)d_ws + xbytes);
        _Float16* W1sw  = Wall;
        _Float16* W2sw  = Wall + W1SW_ELEMS;
        _Float16* cW1sw = Wall + W1SW_ELEMS + W2SW_ELEMS;
        _Float16* cW2sw = Wall + W1SW_ELEMS + W2SW_ELEMS + CW1_ELEMS;

        prep_all<<<(WALL_ELEMS + 255) / 256, 256, 0, stream>>>(
            gW1, mW1, mW2, cgW1, cmW1, cmW2, Wall);
        for (int l = 0; l < NL; ++l)
            layer_wave<<<layer_blocks, 256, 0, stream>>>(x, W1sw, W2sw,
                                                         gb1, gb2, mb1, mb2, gW2, gpw, wts,
                                                         l, l * NH, N);
        pool_mfma<<<C / CB, 256, 0, stream>>>(x, cW1sw, cW2sw,
                                              cgb1, cgb2, cmb1, cmb2, cgW2, cpw, wts,
                                              (float*)d_out);
    } else {
        // ---- fallback: per-layer prep into d_out scratch ----
        _Float16* W1sw = (_Float16*)d_out;
        _Float16* W2sw = (_Float16*)((char*)d_out + 393216);
        for (int l = 0; l < NL; ++l) {
            prep_layer<<<(W1L_ELEMS + W2L_ELEMS) / 256, 256, 0, stream>>>(
                gW1, mW1, mW2, W1sw, W2sw, l);
            layer_wave<<<layer_blocks, 256, 0, stream>>>(x, W1sw, W2sw,
                                                         gb1, gb2, mb1, mb2, gW2, gpw, wts,
                                                         l, 0, N);
        }
        pool_kernel<<<C, 256, 0, stream>>>(x, cgW1, cgb1, cgW2, cgb2,
                                           cmW1, cmb1, cmW2, cmb2, cpw, wts,
                                           (float*)d_out);
    }
}